// Round 5
// baseline (557.241 us; speedup 1.0000x reference)
//
#include <hip/hip_runtime.h>
#include <hip/hip_bf16.h>

// Problem constants
#define Mdim 2048
#define Ndim 8192
#define Kdim 8192
#define BM 128
#define BN 128
#define BK 64

typedef __bf16 bf16x8 __attribute__((ext_vector_type(8)));
typedef float f32x4 __attribute__((ext_vector_type(4)));
typedef unsigned short ushort8 __attribute__((ext_vector_type(8)));
typedef unsigned short ushort4v __attribute__((ext_vector_type(4)));

__device__ __forceinline__ unsigned short f2bf_rne(float f) {
    unsigned u = __float_as_uint(f);
    u += 0x7fffu + ((u >> 16) & 1u);
    return (unsigned short)(u >> 16);
}

__device__ __forceinline__ ushort8 decode8(unsigned bits, float4 c0, float4 c1) {
    ushort8 o;
#pragma unroll
    for (int i = 0; i < 8; ++i) {
        unsigned id = (bits >> (3 * i)) & 7u;
        float a0 = (id & 1) ? c0.y : c0.x;
        float a1 = (id & 1) ? c0.w : c0.z;
        float a2 = (id & 1) ? c1.y : c1.x;
        float a3 = (id & 1) ? c1.w : c1.z;
        float b0 = (id & 2) ? a1 : a0;
        float b1 = (id & 2) ? a3 : a2;
        float v  = (id & 4) ? b1 : b0;
        o[i] = f2bf_rne(v);
    }
    return o;
}

// ---------------------------------------------------------------------------
// Fused prep, LDS-free (at BW floor; r1-r4 showed prep variants are all
// equivalent — non-GEMM time is dominated by fixed harness reset traffic).
// Blocks [0,16384): dequant, 2 groups/thread via 3 aligned int2 loads.
// Blocks [16384,32768): x fp32->bf16, one float4 -> ushort4 per thread.
// ---------------------------------------------------------------------------
__global__ __launch_bounds__(256) void k_prep(const int* __restrict__ packed,
                                              const float* __restrict__ cb,
                                              const float* __restrict__ x,
                                              unsigned short* __restrict__ W,
                                              unsigned short* __restrict__ xb) {
    const int t = threadIdx.x;
    if (blockIdx.x < 16384) {
        const size_t th = (size_t)blockIdx.x * 256 + t;    // 0..4194303
        const size_t g0 = th * 2;                          // even group
        const int2* pv = (const int2*)(packed + g0 * 3);   // 6 ints, 8B aligned
        int2 q0 = pv[0], q1 = pv[1], q2 = pv[2];
        unsigned bits0 = (unsigned)(q0.x & 255) | ((unsigned)(q0.y & 255) << 8) |
                         ((unsigned)(q1.x & 255) << 16);
        unsigned bits1 = (unsigned)(q1.y & 255) | ((unsigned)(q2.x & 255) << 8) |
                         ((unsigned)(q2.y & 255) << 16);
        const float4* cv0 = (const float4*)(cb + ((g0 >> 4) << 3));
        const float4* cv1 = (const float4*)(cb + (((g0 + 1) >> 4) << 3));
        float4 c00 = cv0[0], c01 = cv0[1];
        float4 c10 = cv1[0], c11 = cv1[1];
        ushort8 o0 = decode8(bits0, c00, c01);
        ushort8 o1 = decode8(bits1, c10, c11);
        unsigned short* wp = W + (g0 << 3);                // 32B contiguous
        *(ushort8*)(wp)     = o0;
        *(ushort8*)(wp + 8) = o1;
    } else {
        const size_t u = (size_t)(blockIdx.x - 16384) * 256 + t;  // 0..4194303
        float4 a = ((const float4*)x)[u];
        ushort4v o;
        o[0] = f2bf_rne(a.x); o[1] = f2bf_rne(a.y);
        o[2] = f2bf_rne(a.z); o[3] = f2bf_rne(a.w);
        ((ushort4v*)xb)[u] = o;
    }
}

// ---------------------------------------------------------------------------
// bf16 GEMM  C[M,N] = A[M,K] * B[N,K]^T  (both K-major) — m97-plateau
// structure (873 TF here): 128x128 tile, BK=64, 4 waves (2x2), each 64x64
// via 4x4 mfma 16x16x32. LDS XOR-swizzle at 16B-chunk granularity (bank
// conflicts measured 0). global_load_lds dest = base+lane*16 (required);
// swizzle encoded in per-lane GLOBAL source column.
// Grid orientation: bm on blockIdx.x (16-wide) so consecutive blocks share
// one 2MB W panel (L2-resident) and sweep the LLC-hot 32MB X — W streams
// from HBM once instead of leaking ~375MB of LLC evictions per dispatch.
// ---------------------------------------------------------------------------
__device__ __forceinline__ void gld16(const unsigned short* g, unsigned short* l) {
    __builtin_amdgcn_global_load_lds(
        (const __attribute__((address_space(1))) unsigned int*)g,
        (__attribute__((address_space(3))) unsigned int*)l, 16, 0, 0);
}

__global__ __launch_bounds__(256) void k_gemm(const unsigned short* __restrict__ A,
                                              const unsigned short* __restrict__ B,
                                              float* __restrict__ C) {
    __shared__ unsigned short As[BM * BK];   // 16 KB
    __shared__ unsigned short Bs[BN * BK];   // 16 KB

    const int tid  = threadIdx.x;
    const int lane = tid & 63;
    const int wave = tid >> 6;
    const int waveM = wave >> 1;             // 0..1
    const int waveN = wave & 1;              // 0..1
    const int bm = blockIdx.x * BM;          // bm-fastest for W-panel locality
    const int bn = blockIdx.y * BN;

    const int srow = tid >> 3;                               // 0..31
    const int scol = (((tid & 7) ^ ((tid >> 3) & 7))) * 8;   // swizzled k-chunk
    const unsigned short* agp = A + (size_t)(bm + srow) * Kdim + scol;
    const unsigned short* bgp = B + (size_t)(bn + srow) * Kdim + scol;
    unsigned short* alp = &As[tid * 8];
    unsigned short* blp = &Bs[tid * 8];

    f32x4 acc[4][4];
    const f32x4 zero = {0.f, 0.f, 0.f, 0.f};
#pragma unroll
    for (int i = 0; i < 4; ++i)
#pragma unroll
        for (int j = 0; j < 4; ++j) acc[i][j] = zero;

    const int r15 = lane & 15;
    const int q   = lane >> 4;               // 0..3
    const int rlo = r15 & 7;                 // row&7 for all fragment rows

    for (int kt = 0; kt < Kdim; kt += BK) {
#pragma unroll
        for (int j = 0; j < 4; ++j) {
            gld16(agp + (size_t)(j * 32) * Kdim + kt, alp + j * 2048);
            gld16(bgp + (size_t)(j * 32) * Kdim + kt, blp + j * 2048);
        }
        __syncthreads();

#pragma unroll
        for (int kk = 0; kk < 2; ++kk) {
            const int slot = ((kk * 4 + q) ^ rlo) * 8;   // swizzled LDS slot
            bf16x8 af[4], bfr[4];
#pragma unroll
            for (int i = 0; i < 4; ++i)
                af[i] = *(const bf16x8*)(&As[(waveM * 64 + i * 16 + r15) * BK + slot]);
#pragma unroll
            for (int j = 0; j < 4; ++j)
                bfr[j] = *(const bf16x8*)(&Bs[(waveN * 64 + j * 16 + r15) * BK + slot]);
#pragma unroll
            for (int i = 0; i < 4; ++i)
#pragma unroll
                for (int j = 0; j < 4; ++j)
                    acc[i][j] = __builtin_amdgcn_mfma_f32_16x16x32_bf16(
                        af[i], bfr[j], acc[i][j], 0, 0, 0);
        }
        __syncthreads();
    }

    // Epilogue: C/D layout col = lane&15, row = (lane>>4)*4 + r  (m89/m91)
#pragma unroll
    for (int i = 0; i < 4; ++i) {
#pragma unroll
        for (int j = 0; j < 4; ++j) {
            int row = bm + waveM * 64 + i * 16 + q * 4;
            int col = bn + waveN * 64 + j * 16 + r15;
            float* outp = C + (size_t)row * Ndim + col;
#pragma unroll
            for (int r = 0; r < 4; ++r)
                outp[(size_t)r * Ndim] = acc[i][j][r];
        }
    }
}

// ---------------------------------------------------------------------------
extern "C" void kernel_launch(void* const* d_in, const int* in_sizes, int n_in,
                              void* d_out, int out_size, void* d_ws, size_t ws_size,
                              hipStream_t stream) {
    const float* x      = (const float*)d_in[0];   // 2048 x 8192 fp32
    const int*   packed = (const int*)d_in[1];     // 25165824 int32 (one byte each)
    const float* cb     = (const float*)d_in[2];   // 524288 x 8 fp32
    float* out = (float*)d_out;                    // 2048 x 8192 fp32

    unsigned short* Wb = (unsigned short*)d_ws;                          // 128 MB bf16 W
    unsigned short* Xb = (unsigned short*)d_ws + (size_t)Ndim * Kdim;    // 32 MB bf16 x

    // 1) fused prep: dequant (blocks 0..16383) + x convert (16384..32767)
    k_prep<<<32768, 256, 0, stream>>>(packed, cb, x, Wb, Xb);
    // 2) GEMM — bm-fastest grid for W-panel L2 locality
    dim3 grid(Mdim / BM, Ndim / BN);   // (16, 64)
    k_gemm<<<grid, 256, 0, stream>>>(Xb, Wb, out);
}